// Round 6
// baseline (107.591 us; speedup 1.0000x reference)
//
#include <hip/hip_runtime.h>

constexpr int Fdim = 2000;
constexpr int Wdim = 4000;
constexpr int Edim = 16;
constexpr int Hdim = 64;
constexpr int Bdim = 256;
constexpr int FTILE = 4;      // f-rows per block
constexpr int WCHUNKS = 4;    // w-chunks (blockIdx.y)
constexpr int WTILE = 1024;   // w's per chunk; last chunk short (928)
constexpr int NW = 4;         // CONSECUTIVE w's per thread
constexpr int NQ = Hdim / 4;  // 16 h-quads
constexpr float kLog2e = 1.4426950408889634f;

typedef float v2f __attribute__((ext_vector_type(2)));

__device__ __forceinline__ float fast_exp2(float x) {
#if __has_builtin(__builtin_amdgcn_exp2f)
  return __builtin_amdgcn_exp2f(x);
#else
  return exp2f(x);
#endif
}
__device__ __forceinline__ float fast_rcp(float x) {
#if __has_builtin(__builtin_amdgcn_rcpf)
  return __builtin_amdgcn_rcpf(x);
#else
  return 1.0f / x;
#endif
}
__device__ __forceinline__ v2f v2s(float x) {
  v2f r; r.x = x; r.y = x; return r;
}
__device__ __forceinline__ v2f v2fma(v2f a, v2f b, v2f c) {
  return __builtin_elementwise_fma(a, b, c);
}
__device__ __forceinline__ float4 f4_fma_s(float s, float4 a, float4 b) {
  return make_float4(fmaf(s, a.x, b.x), fmaf(s, a.y, b.y),
                     fmaf(s, a.z, b.z), fmaf(s, a.w, b.w));
}

// ---- DPP wave-64 sum (VALU pipe). Result valid in lane 63.
template <int CTRL>
__device__ __forceinline__ float dpp_part(float x) {
  return __int_as_float(
      __builtin_amdgcn_update_dpp(0, __float_as_int(x), CTRL, 0xF, 0xF, true));
}
__device__ __forceinline__ float wave64_sum(float x) {
  const float x0 = x;
  x += dpp_part<0x111>(x0);  // row_shr:1
  x += dpp_part<0x112>(x0);  // row_shr:2
  x += dpp_part<0x113>(x0);  // row_shr:3
  x += dpp_part<0x114>(x);   // row_shr:4
  x += dpp_part<0x118>(x);   // row_shr:8
  x += dpp_part<0x142>(x);   // row_bcast:15
  x += dpp_part<0x143>(x);   // row_bcast:31
  return x;                  // lane 63 holds the full sum
}

// --- prep (fused):
//   efp[f][h]  = exp2( (femb@Ww[:E] + b) * 2log2e )
//   ehp4[q][w] = float4( exp2(S*hid[4q+k][w]) k=0..3 )   (h-QUAD interleaved)
//   wusum = sum(Wu)
//   mflag = mask-layout detect (1 = byte bool, 0 = int32)
__global__ __launch_bounds__(256) void prep_kernel(
    const float* __restrict__ femb, const float* __restrict__ hemb,
    const float* __restrict__ Ww, const float* __restrict__ bw,
    const float* __restrict__ Wu, const unsigned char* __restrict__ mask,
    float* __restrict__ efp, float* __restrict__ ehp4,
    float* __restrict__ wusum, int* __restrict__ mflag) {
  constexpr float S = 2.0f * kLog2e;
  constexpr int NF = Fdim * Hdim;   // 128000
  constexpr int NH4 = NQ * Wdim;    // 64000 (one thread per (h-quad, w))
  int idx = blockIdx.x * 256 + threadIdx.x;
  if (idx < NF) {
    int f = idx >> 6, h = idx & 63;
    float acc = bw[h];
#pragma unroll
    for (int e = 0; e < Edim; ++e)
      acc = fmaf(femb[f * Edim + e], Ww[e * Hdim + h], acc);
    efp[idx] = fast_exp2(acc * S);
  } else if (idx < NF + NH4) {
    int j = idx - NF;
    int q = j / Wdim, w = j - q * Wdim;
    float4 a = make_float4(0.f, 0.f, 0.f, 0.f);
#pragma unroll
    for (int e = 0; e < Edim; ++e) {
      float he = hemb[w * Edim + e];
      float4 wr = *(const float4*)(Ww + (Edim + e) * Hdim + 4 * q);
      a = f4_fma_s(he, wr, a);
    }
    ((float4*)ehp4)[q * Wdim + w] =
        make_float4(fast_exp2(a.x * S), fast_exp2(a.y * S),
                    fast_exp2(a.z * S), fast_exp2(a.w * S));
  } else if (idx < NF + NH4 + 64) {
    int l = idx - (NF + NH4);       // wave 0 of block 750 (192000/256=750)
    float s = Wu[l];
#pragma unroll
    for (int o = 32; o > 0; o >>= 1) s += __shfl_down(s, o, 64);
    if (l == 0) *wusum = s;
  } else if (idx < NF + NH4 + 128) {
    // mask layout detect: bytes at i%4!=0 all zero <=> int32 layout
    int l = idx - (NF + NH4 + 64);  // wave 1 of block 750
    int acc = 0;
    for (int i = l; i < 8192; i += 64)
      if ((i & 3) != 0) acc |= mask[i];
    unsigned long long b = __ballot(acc != 0);
    if (l == 0) *mflag = (b != 0ull) ? 1 : 0;
  }
}

// --- main: block = (f-tile, w-chunk). Thread owns NW=4 CONSECUTIVE w's.
// Quad-h under one rcp, VOP3P-packed across fi pairs:
//   sum_k wu_k/d_k = [ (wu0*d1+wu1*d0)*d2*d3 + (wu2*d3+wu3*d2)*d0*d1 ]
//                    / (d0*d1*d2*d3),   d_k = 1 + efp[f][4q+k]*ehp[4q+k][w]
// sc = mask * exp2(wls - log2e * sneg)
__global__ __launch_bounds__(256, 4) void attn_ctx_kernel(
    const float* __restrict__ efp, const float* __restrict__ ehp4,
    const float* __restrict__ Wu, const float* __restrict__ wusum_p,
    const unsigned char* mask_b, const int* __restrict__ mflag,
    const float* __restrict__ hemb, float* __restrict__ part) {
  const int f0 = blockIdx.x * FTILE;
  const int chunk = blockIdx.y;
  const int tid = threadIdx.x;

  __shared__ float4 s_fp4[Hdim];               // efp over fi, per h
  __shared__ __align__(16) float s_wu[Hdim];   // 2*Wu[h]
  __shared__ float s_red[4][FTILE][20];        // [wave][fi][16 num + den@16]

  if (tid < Hdim) {
    s_wu[tid] = 2.0f * Wu[tid];
    float a = efp[(f0 + 0) * Hdim + tid];
    float b = efp[(f0 + 1) * Hdim + tid];
    float c = efp[(f0 + 2) * Hdim + tid];
    float d = efp[(f0 + 3) * Hdim + tid];
    s_fp4[tid] = make_float4(a, b, c, d);
  }
  __syncthreads();

  const int mbyte = *mflag;
  const float wls = (*wusum_p) * kLog2e;

  const int w0 = chunk * WTILE + tid * NW;
  const bool wok = (w0 < Wdim);           // Wdim%4==0 -> all-or-nothing
  const int wcl = wok ? w0 : (Wdim - NW); // clamped for safe loads

  // sneg2[p][j]: v2f over fi-pair p = (2p, 2p+1), w index j
  v2f sneg2[2][NW];
#pragma unroll
  for (int p = 0; p < 2; ++p)
#pragma unroll
    for (int j = 0; j < NW; ++j) sneg2[p][j] = v2s(0.f);

  const float4* erow = (const float4*)ehp4 + wcl;  // element (q,w): q*Wdim+w

  // ---- h-quad main loop: 4 dwordx4 + 5 LDS b128 per q
#pragma unroll 2
  for (int q = 0; q < NQ; ++q) {
    float4 L[NW];
#pragma unroll
    for (int j = 0; j < NW; ++j) L[j] = erow[q * Wdim + j];
    float4 wuq = *(const float4*)&s_wu[4 * q];
    float wu[4] = {wuq.x, wuq.y, wuq.z, wuq.w};
    v2f fp[4][2];
#pragma unroll
    for (int k = 0; k < 4; ++k) {
      float4 t = s_fp4[4 * q + k];
      fp[k][0].x = t.x; fp[k][0].y = t.y;
      fp[k][1].x = t.z; fp[k][1].y = t.w;
    }
#pragma unroll
    for (int j = 0; j < NW; ++j) {
      float e0 = L[j].x, e1 = L[j].y, e2 = L[j].z, e3 = L[j].w;
#pragma unroll
      for (int p = 0; p < 2; ++p) {
        v2f d0 = v2fma(fp[0][p], v2s(e0), v2s(1.f));
        v2f d1 = v2fma(fp[1][p], v2s(e1), v2s(1.f));
        v2f d2 = v2fma(fp[2][p], v2s(e2), v2s(1.f));
        v2f d3 = v2fma(fp[3][p], v2s(e3), v2s(1.f));
        v2f p01 = d0 * d1, p23 = d2 * d3;
        v2f n01 = v2fma(v2s(wu[1]), d0, v2s(wu[0]) * d1);
        v2f n23 = v2fma(v2s(wu[3]), d2, v2s(wu[2]) * d3);
        v2f num = v2fma(n23, p01, n01 * p23);
        v2f den4 = p01 * p23;
        v2f r; r.x = fast_rcp(den4.x); r.y = fast_rcp(den4.y);
        sneg2[p][j] = v2fma(num, r, sneg2[p][j]);
      }
    }
  }

  // ---- mask bits: one uint (byte layout) / uint4 (int layout) per f-row
  float mbit[FTILE][NW];
  if (mbyte) {
#pragma unroll
    for (int fi = 0; fi < FTILE; ++fi) {
      unsigned int m =
          *(const unsigned int*)(mask_b + (size_t)(f0 + fi) * Wdim + wcl);
#pragma unroll
      for (int j = 0; j < NW; ++j)
        mbit[fi][j] = wok ? (float)((m >> (8 * j)) & 1u) : 0.f;
    }
  } else {
    const int* mask_i = (const int*)mask_b;
#pragma unroll
    for (int fi = 0; fi < FTILE; ++fi) {
      uint4 m4 = *(const uint4*)(mask_i + (size_t)(f0 + fi) * Wdim + wcl);
      unsigned int mm[NW] = {m4.x, m4.y, m4.z, m4.w};
#pragma unroll
      for (int j = 0; j < NW; ++j)
        mbit[fi][j] = (wok && mm[j]) ? 1.f : 0.f;
    }
  }

  // ---- score + context accumulation (cacc packed over E)
  float den[FTILE] = {0.f, 0.f, 0.f, 0.f};
  v2f cacc2[FTILE][8];
#pragma unroll
  for (int fi = 0; fi < FTILE; ++fi)
#pragma unroll
    for (int t = 0; t < 8; ++t) cacc2[fi][t] = v2s(0.f);

  const float4* h4 = (const float4*)(hemb + (size_t)wcl * Edim);
#pragma unroll
  for (int j = 0; j < NW; ++j) {
    float4 hr[4] = {h4[j * 4 + 0], h4[j * 4 + 1], h4[j * 4 + 2], h4[j * 4 + 3]};
    v2f hv[8];
#pragma unroll
    for (int t = 0; t < 4; ++t) {
      hv[2 * t].x = hr[t].x;     hv[2 * t].y = hr[t].y;
      hv[2 * t + 1].x = hr[t].z; hv[2 * t + 1].y = hr[t].w;
    }
#pragma unroll
    for (int p = 0; p < 2; ++p) {
      v2f arg = v2fma(sneg2[p][j], v2s(-kLog2e), v2s(wls));
      float sc0 = fast_exp2(arg.x) * mbit[2 * p][j];
      float sc1 = fast_exp2(arg.y) * mbit[2 * p + 1][j];
      den[2 * p] += sc0;
      den[2 * p + 1] += sc1;
#pragma unroll
      for (int t = 0; t < 8; ++t) {
        cacc2[2 * p][t] = v2fma(v2s(sc0), hv[t], cacc2[2 * p][t]);
        cacc2[2 * p + 1][t] = v2fma(v2s(sc1), hv[t], cacc2[2 * p + 1][t]);
      }
    }
  }

  // ---- DPP in-wave reduction, lane 63 -> LDS
  const int lane = tid & 63, wv = tid >> 6;
#pragma unroll
  for (int fi = 0; fi < FTILE; ++fi) {
    float d = wave64_sum(den[fi]);
    if (lane == 63) s_red[wv][fi][16] = d;
#pragma unroll
    for (int t = 0; t < 8; ++t) {
      float a = wave64_sum(cacc2[fi][t].x);
      float b = wave64_sum(cacc2[fi][t].y);
      if (lane == 63) {
        s_red[wv][fi][2 * t] = a;
        s_red[wv][fi][2 * t + 1] = b;
      }
    }
  }
  __syncthreads();
  if (tid < FTILE * 17) {
    int fi = tid / 17, k = tid % 17;
    float tot = s_red[0][fi][k] + s_red[1][fi][k] + s_red[2][fi][k] +
                s_red[3][fi][k];
    part[((f0 + fi) * WCHUNKS + chunk) * 17 + k] = tot;
  }
}

// --- finalize: ctx[f][e] = sum_c num / sum_c den ---------------------------
__global__ __launch_bounds__(256) void finalize_kernel(
    const float* __restrict__ part, float* __restrict__ ctx) {
  int idx = blockIdx.x * 256 + threadIdx.x;
  if (idx >= Fdim * Edim) return;
  int f = idx >> 4, e = idx & 15;
  const float* p = part + f * WCHUNKS * 17;
  float den = 0.f, num = 0.f;
#pragma unroll
  for (int c = 0; c < WCHUNKS; ++c) {
    den += p[c * 17 + 16];
    num += p[c * 17 + e];
  }
  ctx[idx] = num / den;
}

// --- out[b][e] = sum_f values[b][f] * ctx[f][e] ----------------------------
__global__ __launch_bounds__(256) void out_gemv_kernel(
    const float* __restrict__ values, const float* __restrict__ ctx,
    float* __restrict__ out) {
  const int b = blockIdx.x, tid = threadIdx.x;
  float acc[Edim];
#pragma unroll
  for (int e = 0; e < Edim; ++e) acc[e] = 0.f;
  for (int f = tid; f < Fdim; f += 256) {
    float v = values[b * Fdim + f];
    const float4* c4 = (const float4*)(ctx + f * Edim);
    float4 c0 = c4[0], c1 = c4[1], c2 = c4[2], c3 = c4[3];
    float cr[Edim] = {c0.x, c0.y, c0.z, c0.w, c1.x, c1.y, c1.z, c1.w,
                      c2.x, c2.y, c2.z, c2.w, c3.x, c3.y, c3.z, c3.w};
#pragma unroll
    for (int e = 0; e < Edim; ++e) acc[e] = fmaf(v, cr[e], acc[e]);
  }
  __shared__ float s_red[4][Edim];
  const int lane = tid & 63, wv = tid >> 6;
#pragma unroll
  for (int e = 0; e < Edim; ++e) {
    float a = wave64_sum(acc[e]);
    if (lane == 63) s_red[wv][e] = a;
  }
  __syncthreads();
  if (tid < Edim)
    out[b * Edim + tid] =
        s_red[0][tid] + s_red[1][tid] + s_red[2][tid] + s_red[3][tid];
}

extern "C" void kernel_launch(void* const* d_in, const int* in_sizes, int n_in,
                              void* d_out, int out_size, void* d_ws,
                              size_t ws_size, hipStream_t stream) {
  const float* values = (const float*)d_in[0];
  const float* femb   = (const float*)d_in[1];
  const float* hemb   = (const float*)d_in[2];
  const float* Ww     = (const float*)d_in[3];
  const float* bw     = (const float*)d_in[4];
  const float* Wu     = (const float*)d_in[5];
  const unsigned char* mask = (const unsigned char*)d_in[6];
  float* out = (float*)d_out;

  // workspace (floats): efp[F*H] | ehp4[H*W] | ctx[F*E] | wusum | mflag | part
  float* ws = (float*)d_ws;
  float* efp = ws;                                    // 128000
  float* ehp4 = efp + Fdim * Hdim;                    // 256000
  float* ctx = ehp4 + (size_t)Hdim * Wdim;            // 32000
  float* wusum = ctx + Fdim * Edim;                   // 1
  int* mflag = (int*)(wusum + 1);                     // 1
  float* part = (float*)(mflag + 1);                  // 2000*4*17 = 136000

  constexpr int NTOT = Fdim * Hdim + NQ * Wdim + 128;  // 192128
  prep_kernel<<<dim3((NTOT + 255) / 256), dim3(256), 0, stream>>>(
      femb, hemb, Ww, bw, Wu, mask, efp, ehp4, wusum, mflag);

  attn_ctx_kernel<<<dim3(Fdim / FTILE, WCHUNKS), dim3(256), 0, stream>>>(
      efp, ehp4, Wu, wusum, mask, mflag, hemb, part);

  finalize_kernel<<<dim3((Fdim * Edim + 255) / 256), dim3(256), 0, stream>>>(
      part, ctx);

  out_gemv_kernel<<<dim3(Bdim), dim3(256), 0, stream>>>(values, ctx, out);
}